// Round 6
// baseline (690.855 us; speedup 1.0000x reference)
//
#include <hip/hip_runtime.h>
#include <hip/hip_bf16.h>

typedef __bf16 bf16_t;
typedef __bf16 bf16x8 __attribute__((ext_vector_type(8)));
typedef float f32x4 __attribute__((ext_vector_type(4)));

#define B_  4
#define S_  2048
#define H_  16
#define DK_ 128
#define DM_ 2048
#define BS_ (B_ * S_)          // 8192 rows

static __device__ __forceinline__ f32x4 mfma16(bf16x8 a, bf16x8 b, f32x4 c) {
  return __builtin_amdgcn_mfma_f32_16x16x32_bf16(a, b, c, 0, 0, 0);
}

// async global->LDS 16B copy. lds base must be wave-uniform; HW scatters lane*16.
static __device__ __forceinline__ void async_copy16(const bf16_t* g, bf16_t* l) {
  __builtin_amdgcn_global_load_lds(
      (const __attribute__((address_space(1))) void*)g,
      (__attribute__((address_space(3))) void*)l, 16, 0, 0);
}

// DPP row_ror (within 16-lane row) on f32 -- cross-lane reduce on the VALU pipe.
template <int CTRL>
static __device__ __forceinline__ float dpp_rorf(float x) {
  return __builtin_bit_cast(float,
      __builtin_amdgcn_update_dpp(0, __builtin_bit_cast(int, x), CTRL, 0xF, 0xF, true));
}
static __device__ __forceinline__ float rowmax16(float r) {
  r = fmaxf(r, dpp_rorf<0x121>(r));
  r = fmaxf(r, dpp_rorf<0x122>(r));
  r = fmaxf(r, dpp_rorf<0x124>(r));
  r = fmaxf(r, dpp_rorf<0x128>(r));
  return r;
}
static __device__ __forceinline__ float rowsum16(float r) {
  r += dpp_rorf<0x121>(r);
  r += dpp_rorf<0x122>(r);
  r += dpp_rorf<0x124>(r);
  r += dpp_rorf<0x128>(r);
  return r;
}

struct ChainOn  { static constexpr bool v = true;  };
struct ChainOff { static constexpr bool v = false; };

// ---------------------------------------------------------------------------
// fp32 -> bf16 elementwise convert (8 elems/thread)
// ---------------------------------------------------------------------------
__global__ __launch_bounds__(256) void cvt_bf16(const float* __restrict__ in,
                                                bf16_t* __restrict__ out, int n8) {
  int i = blockIdx.x * 256 + threadIdx.x;
  if (i < n8) {
    const float4* p = (const float4*)in + (size_t)i * 2;
    float4 f0 = p[0], f1 = p[1];
    bf16x8 r;
    r[0] = (bf16_t)f0.x; r[1] = (bf16_t)f0.y; r[2] = (bf16_t)f0.z; r[3] = (bf16_t)f0.w;
    r[4] = (bf16_t)f1.x; r[5] = (bf16_t)f1.y; r[6] = (bf16_t)f1.z; r[7] = (bf16_t)f1.w;
    ((bf16x8*)out)[i] = r;
  }
}

// ---------------------------------------------------------------------------
// C[M,N] = A[M,K] * B[N,K]^T -- 256x256 tile, BK=64, 8 waves (2M x 4N),
// 4-phase-per-K-tile deep pipeline (T3+T4): K-half-granular LDS buffering
// [dbuf][khalf][256][32], per phase {ds_read quadrant | 2x global_load_lds |
// barrier | setprio(1) 16 MFMA setprio(0) | barrier}, counted s_waitcnt
// vmcnt(8) ONLY at phases 1 and 3 (never 0 in the main loop).
//
// Ledger (per wave, 2 loads/phase; issues p0:A-kh1(t+1) p1:B-kh1(t+1)
// p2:A-kh0(t+2) p3:B-kh0(t+2)):
//   W1 (end p1, vmcnt(8)): drains t-1 p0,p1 = kh1(t)  -> read at phases 2,3.
//   W2 (end p3, vmcnt(8)): drains t-1 p2,p3 = kh0(t+1)-> read at t+1 phase 0.
// Overwrite safety: p2 stages into [cur][kh0] whose last reads (phase 1)
// completed before phase-1 barrier2; stage is issued after it. Epilogue tiles
// always-issue with K-source clamped into provably-dead slots (uniform ledger).
//
// Swizzle (T2): LDS row = 32 cols = 4 chunks of 8; logical chunk q stored at
// p = q ^ s(r), s(r) = (r + (r>>2)) & 3. global_load_lds dest stays linear;
// SOURCE chunk is inverse-swizzled (same XOR); ds_read applies the XOR.
// Frag reads: 16 lanes hit 8 (parity,p) combos x 2 rows 8 apart = 2-way (free).
// VTOUT: write C per-head-transposed into Vt layout [(b*16+h)*128+d][s].
// ---------------------------------------------------------------------------
template <typename TC, bool VTOUT>
__global__ __launch_bounds__(512, 2) void gemm256(const bf16_t* __restrict__ A,
                                                  const bf16_t* __restrict__ B,
                                                  TC* __restrict__ C,
                                                  int M, int N, int K) {
  __shared__ bf16_t Ab[2][2][256 * 32];   // [dbuf][khalf][row*32+col] 64 KiB
  __shared__ bf16_t Bb[2][2][256 * 32];   // 64 KiB

  const int tid  = threadIdx.x;
  const int wave = tid >> 6;              // 0..7
  const int lane = tid & 63;
  const int quad = lane >> 4;
  const int l16  = lane & 15;
  const int wm   = (wave >> 2) * 128;     // wave's A half (M)
  const int wn   = (wave & 3) * 64;       // wave's B quarter (N)

  // XCD-bijective remap: 256 blocks; xcd owns a contiguous 4x8 tile stripe.
  const int bid = (int)blockIdx.x;
  const int xcd = bid & 7;
  const int idx = bid >> 3;               // 0..31
  const int bm  = (xcd * 4 + (idx >> 3)) * 256;
  const int bn  = (idx & 7) * 256;

  // --- staging geometry (per kh-stage: 2 instructions/wave, 16 rows each) ---
  const int p_ = lane & 3;                // chunk-in-row the HW writes
  const int r0 = wave * 32 + (lane >> 2); // instruction 0 row
  const int r1 = r0 + 16;                 // instruction 1 row
  const int s0 = (r0 + (r0 >> 2)) & 3;
  const int s1 = (r1 + (r1 >> 2)) & 3;
  const size_t aO0 = (size_t)(bm + r0) * K + (p_ ^ s0) * 8;
  const size_t aO1 = (size_t)(bm + r1) * K + (p_ ^ s1) * 8;
  const size_t bO0 = (size_t)(bn + r0) * K + (p_ ^ s0) * 8;
  const size_t bO1 = (size_t)(bn + r1) * K + (p_ ^ s1) * 8;
  const int ldsW = wave * 1024;           // wave-uniform elem base (+512 for i1)

  auto stA = [&](int slot, int kh, int kt) __attribute__((always_inline)) {
    const int c = kt * 64 + kh * 32;
    bf16_t* d = &Ab[slot][kh][ldsW];
    async_copy16(A + aO0 + c, d);
    async_copy16(A + aO1 + c, d + 512);
  };
  auto stB = [&](int slot, int kh, int kt) __attribute__((always_inline)) {
    const int c = kt * 64 + kh * 32;
    bf16_t* d = &Bb[slot][kh][ldsW];
    async_copy16(B + bO0 + c, d);
    async_copy16(B + bO1 + c, d + 512);
  };

  // --- fragment-read bases (s(row) is lane-only for 16-aligned row bases) ---
  const int sw  = (l16 + (l16 >> 2)) & 3;
  const int qs  = (quad ^ sw) * 8;
  const int arB = (wm + l16) * 32 + qs;   // + i*512 (+2048 for m-half 1)
  const int brB = (wn + l16) * 32 + qs;   // + n*512

  f32x4 acc[8][4];
#pragma unroll
  for (int i = 0; i < 8; ++i)
#pragma unroll
    for (int j = 0; j < 4; ++j) acc[i][j] = (f32x4){0.f, 0.f, 0.f, 0.f};

  const int NT = K >> 6;                  // K-tiles (BK=64)

  // prologue: kh0(0), kh1(0) -> buf0; kh0(1) -> buf1. 12 loads/wave.
  stA(0, 0, 0); stB(0, 0, 0);
  stA(0, 1, 0); stB(0, 1, 0);
  { int k1 = NT > 1 ? 1 : 0; stA(1, 0, k1); stB(1, 0, k1); }
  asm volatile("s_waitcnt vmcnt(8)" ::: "memory");   // kh0(0) resident
  __syncthreads();

  for (int t = 0; t < NT; ++t) {
    const int cur = t & 1, nxt = cur ^ 1;
    const int tp1 = (t + 1 < NT) ? t + 1 : NT - 1;   // clamped sources
    const int tp2 = (t + 2 < NT) ? t + 2 : NT - 1;
    bf16x8 af[4], bfr[4];

    // ---- phase 0: ks=0, m-half 0 | stage A-kh1(t+1) ----
#pragma unroll
    for (int i = 0; i < 4; ++i)
      af[i] = *(const bf16x8*)(&Ab[cur][0][arB + i * 512]);
#pragma unroll
    for (int n = 0; n < 4; ++n)
      bfr[n] = *(const bf16x8*)(&Bb[cur][0][brB + n * 512]);
    stA(nxt, 1, tp1);
    __syncthreads();
    __builtin_amdgcn_s_setprio(1);
#pragma unroll
    for (int i = 0; i < 4; ++i)
#pragma unroll
      for (int n = 0; n < 4; ++n) acc[i][n] = mfma16(af[i], bfr[n], acc[i][n]);
    __builtin_amdgcn_s_setprio(0);
    __syncthreads();

    // ---- phase 1: ks=0, m-half 1 | stage B-kh1(t+1) | W1 ----
#pragma unroll
    for (int i = 0; i < 4; ++i)
      af[i] = *(const bf16x8*)(&Ab[cur][0][arB + 2048 + i * 512]);
    stB(nxt, 1, tp1);
    __syncthreads();
    __builtin_amdgcn_s_setprio(1);
#pragma unroll
    for (int i = 0; i < 4; ++i)
#pragma unroll
      for (int n = 0; n < 4; ++n)
        acc[4 + i][n] = mfma16(af[i], bfr[n], acc[4 + i][n]);
    __builtin_amdgcn_s_setprio(0);
    asm volatile("s_waitcnt vmcnt(8)" ::: "memory");  // kh1(t) resident
    __syncthreads();

    // ---- phase 2: ks=1, m-half 0 | stage A-kh0(t+2) ----
#pragma unroll
    for (int i = 0; i < 4; ++i)
      af[i] = *(const bf16x8*)(&Ab[cur][1][arB + i * 512]);
#pragma unroll
    for (int n = 0; n < 4; ++n)
      bfr[n] = *(const bf16x8*)(&Bb[cur][1][brB + n * 512]);
    stA(cur, 0, tp2);
    __syncthreads();
    __builtin_amdgcn_s_setprio(1);
#pragma unroll
    for (int i = 0; i < 4; ++i)
#pragma unroll
      for (int n = 0; n < 4; ++n) acc[i][n] = mfma16(af[i], bfr[n], acc[i][n]);
    __builtin_amdgcn_s_setprio(0);
    __syncthreads();

    // ---- phase 3: ks=1, m-half 1 | stage B-kh0(t+2) | W2 ----
#pragma unroll
    for (int i = 0; i < 4; ++i)
      af[i] = *(const bf16x8*)(&Ab[cur][1][arB + 2048 + i * 512]);
    stB(cur, 0, tp2);
    __syncthreads();
    __builtin_amdgcn_s_setprio(1);
#pragma unroll
    for (int i = 0; i < 4; ++i)
#pragma unroll
      for (int n = 0; n < 4; ++n)
        acc[4 + i][n] = mfma16(af[i], bfr[n], acc[4 + i][n]);
    __builtin_amdgcn_s_setprio(0);
    asm volatile("s_waitcnt vmcnt(8)" ::: "memory");  // kh0(t+1) resident
    __syncthreads();
  }

  // epilogue: C/D layout row = quad*4+v, col = l16 per 16x16 fragment
#pragma unroll
  for (int mt = 0; mt < 8; ++mt)
#pragma unroll
    for (int nt = 0; nt < 4; ++nt)
#pragma unroll
      for (int v = 0; v < 4; ++v) {
        int row = bm + wm + mt * 16 + quad * 4 + v;
        int col = bn + wn + nt * 16 + l16;
        if constexpr (VTOUT) {
          // row = b*S+s, col = h*128+d -> Vt[((b*16+h)*128+d)*S + s]
          size_t o = (size_t)(((row >> 11) * 16 + (col >> 7)) * 128 + (col & 127)) * S_ +
                     (row & 2047);
          C[o] = (TC)acc[mt][nt][v];
        } else {
          C[(size_t)row * N + col] = (TC)acc[mt][nt][v];
        }
      }
}

// ---------------------------------------------------------------------------
// Flash attention, dual-chain load-balanced version (measured 153.9 us r5):
//  * One workgroup owns TWO q-blocks {qa=31-p, qc=p}: constant 33 work-units.
//  * Both chains consume the SAME staged K/V tile (shared kf/vf ds_reads).
//  * K/V double-buffered, global_load_lds issued one tile ahead.
//  * XOR-swizzled LDS, inverse-swizzled global sources.
//  * DPP row_ror softmax reductions; Q direct global->reg; defer-max; setprio.
// LDS: Ks 32K + Vs 32K + Ps 16K = 80KB -> 2 blocks/CU.
// Q,K: [b*S+s][h*128+d] bf16.  VT: [(b*16+h)*128+d][s] bf16.  O like Q.
// ---------------------------------------------------------------------------
__global__ __launch_bounds__(256, 2) void attn_kernel(const bf16_t* __restrict__ Q,
                                                      const bf16_t* __restrict__ K,
                                                      const bf16_t* __restrict__ VT,
                                                      bf16_t* __restrict__ O,
                                                      const int* __restrict__ use_mask) {
  __shared__ bf16_t Ks[2 * 64 * 128];   // [buf][k][d], XOR-swizzled
  __shared__ bf16_t Vs[2 * 128 * 64];   // [buf][d][k], XOR-swizzled
  __shared__ bf16_t Ps[2 * 4 * 16 * 64];// [chain][wave][16][64], XOR-swizzled

  const int tid  = threadIdx.x;
  const int wave = tid >> 6;
  const int lane = tid & 63;
  const int quad = lane >> 4;
  const int l16  = lane & 15;

  const int lid  = (int)(blockIdx.y * gridDim.x + blockIdx.x);
  const int xcd  = lid & 7;
  const int t8   = lid >> 3;                 // 0..127
  const int bh   = xcd + ((t8 >> 4) << 3);   // 8 heads per XCD
  const int pair = t8 & 15;
  const int qa   = 31 - pair;                // heavy q-block (17..32 tiles)
  const int qc   = pair;                     // light q-block (1..16 tiles)
  const int b = bh >> 4, h = bh & 15;
  const int maskflag = *use_mask;

  const size_t qbaseA = ((size_t)b * S_ + (size_t)qa * 64) * DM_ + h * DK_;
  const size_t qbaseC = ((size_t)b * S_ + (size_t)qc * 64) * DM_ + h * DK_;

  int skO[4], svO[4];
#pragma unroll
  for (int p = 0; p < 4; ++p) {
    int rK = p * 16 + wave * 4 + quad;
    skO[p] = rK * DM_ + ((l16 ^ (rK & 7)) * 8);
    int dV = p * 32 + wave * 8 + (lane >> 3);
    svO[p] = dV * S_ + (((lane & 7) ^ (dV & 7)) * 8);
  }

  const bf16_t* Kbase = K + (size_t)b * S_ * DM_ + h * DK_;
  const bf16_t* Vbase = VT + (size_t)bh * DK_ * S_;

  auto stage_kv = [&](int j, int buf) __attribute__((always_inline)) {
    const bf16_t* kb = Kbase + (size_t)j * 64 * DM_;
    const bf16_t* vb = Vbase + (size_t)j * 64;
    bf16_t* kl = Ks + buf * 8192 + wave * 512;
    bf16_t* vl = Vs + buf * 8192 + wave * 512;
#pragma unroll
    for (int p = 0; p < 4; ++p) {
      async_copy16(kb + skO[p], kl + p * 2048);
      async_copy16(vb + svO[p], vl + p * 2048);
    }
  };

  bf16x8 qfA[4], qfC[4];
#pragma unroll
  for (int kk = 0; kk < 4; ++kk) {
    size_t ro = (size_t)(wave * 16 + l16) * DM_ + kk * 32 + quad * 8;
    qfA[kk] = *(const bf16x8*)(Q + qbaseA + ro);
    qfC[kk] = *(const bf16x8*)(Q + qbaseC + ro);
  }

  stage_kv(0, 0);

  f32x4 accA[8], accC[8];
#pragma unroll
  for (int i = 0; i < 8; ++i) {
    accA[i] = (f32x4){0.f, 0.f, 0.f, 0.f};
    accC[i] = (f32x4){0.f, 0.f, 0.f, 0.f};
  }
  float mA[4], lA[4], mC[4], lC[4];
#pragma unroll
  for (int v = 0; v < 4; ++v) {
    mA[v] = -INFINITY; lA[v] = 0.f;
    mC[v] = -INFINITY; lC[v] = 0.f;
  }

  bf16_t* PwA = Ps + wave * 1024;
  bf16_t* PwC = Ps + 4096 + wave * 1024;

  const float c1 = 0.08838834764831845f * 1.4426950408889634f;

  const int ntA = maskflag ? qa + 1 : (S_ / 64);
  const int ntC = maskflag ? qc + 1 : (S_ / 64);

  auto softmax_chain = [&](f32x4 (&s)[4], float (&mrow)[4], float (&lrow)[4],
                           f32x4 (&acc)[8], bf16_t* Pw, bool masked)
      __attribute__((always_inline)) {
#pragma unroll
    for (int v = 0; v < 4; ++v) {
      float x[4];
#pragma unroll
      for (int nt = 0; nt < 4; ++nt) {
        float y = s[nt][v] * c1;
        if (masked) {
          int kg = nt * 16 + l16;
          int qg = wave * 16 + quad * 4 + v;
          if (kg > qg) y = -INFINITY;
        }
        x[nt] = y;
      }
      float r = fmaxf(fmaxf(x[0], x[1]), fmaxf(x[2], x[3]));
      r = rowmax16(r);
      float m = mrow[v];
      if (r > m + 8.f) {
        float alpha = __builtin_amdgcn_exp2f(m - r);
        lrow[v] *= alpha;
#pragma unroll
        for (int dt = 0; dt < 8; ++dt) acc[dt][v] *= alpha;
        mrow[v] = r;
        m = r;
      }
      float rs = 0.f;
      int prow = quad * 4 + v;
#pragma unroll
      for (int nt = 0; nt < 4; ++nt) {
        float p = __builtin_amdgcn_exp2f(x[nt] - m);
        rs += p;
        Pw[prow * 64 + ((nt * 16 + l16) ^ ((prow & 7) << 3))] = (bf16_t)p;
      }
      lrow[v] += rowsum16(rs);
    }
  };

  auto body = [&](auto DOC, int cur, bool maskedA, bool maskedC)
      __attribute__((always_inline)) {
    constexpr bool doC = decltype(DOC)::v;
    const bf16_t* KsB = Ks + cur * 8192;
    const bf16_t* VsB = Vs + cur * 8192;

    f32x4 sA[4], sC[4];
#pragma unroll
    for (int nt = 0; nt < 4; ++nt) {
      sA[nt] = (f32x4){0.f, 0.f, 0.f, 0.f};
      sC[nt] = (f32x4){0.f, 0.f, 0.f, 0.f};
    }
    __builtin_amdgcn_s_setprio(1);
#pragma unroll
    for (int kk = 0; kk < 4; ++kk) {
#pragma unroll
      for (int nt = 0; nt < 4; ++nt) {
        bf16x8 kf = *(const bf16x8*)(KsB + (nt * 16 + l16) * 128 +
                                     ((kk * 32 + quad * 8) ^ ((l16 & 7) << 3)));
        sA[nt] = mfma16(qfA[kk], kf, sA[nt]);
        if constexpr (doC) sC[nt] = mfma16(qfC[kk], kf, sC[nt]);
      }
    }
    __builtin_amdgcn_s_setprio(0);

    softmax_chain(sA, mA, lA, accA, PwA, maskedA);
    if constexpr (doC) softmax_chain(sC, mC, lC, accC, PwC, maskedC);

    __builtin_amdgcn_s_setprio(1);
#pragma unroll
    for (int kk = 0; kk < 2; ++kk) {
      bf16x8 pfA = *(const bf16x8*)(PwA + l16 * 64 +
                                    ((kk * 32 + quad * 8) ^ ((l16 & 7) << 3)));
      bf16x8 pfC = {};
      if constexpr (doC)
        pfC = *(const bf16x8*)(PwC + l16 * 64 +
                               ((kk * 32 + quad * 8) ^ ((l16 & 7) << 3)));
#pragma unroll
      for (int dt = 0; dt < 8; ++dt) {
        bf16x8 vf = *(const bf16x8*)(VsB + (dt * 16 + l16) * 64 +
                                     ((kk * 32 + quad * 8) ^ ((l16 & 7) << 3)));
        accA[dt] = mfma16(pfA, vf, accA[dt]);
        if constexpr (doC) accC[dt] = mfma16(pfC, vf, accC[dt]);
      }
    }
    __builtin_amdgcn_s_setprio(0);
  };

  __syncthreads();

  for (int t = 0; t < ntA; ++t) {
    const int cur = t & 1;
    if (t + 1 < ntA) stage_kv(t + 1, cur ^ 1);
    const bool mAf = maskflag && (t == qa);
    if (t < ntC)
      body(ChainOn{},  cur, mAf, maskflag && (t == qc));
    else
      body(ChainOff{}, cur, mAf, false);
    __syncthreads();
  }

  auto epilogue = [&](f32x4 (&acc)[8], float (&lrow)[4], size_t qbase)
      __attribute__((always_inline)) {
    float rl[4];
#pragma unroll
    for (int v = 0; v < 4; ++v) rl[v] = __builtin_amdgcn_rcpf(lrow[v]);
#pragma unroll
    for (int dt = 0; dt < 8; ++dt)
#pragma unroll
      for (int v = 0; v < 4; ++v) {
        int qr = wave * 16 + quad * 4 + v;
        O[qbase + (size_t)qr * DM_ + dt * 16 + l16] = (bf16_t)(acc[dt][v] * rl[v]);
      }
  };
  epilogue(accA, lA, qbaseA);
  epilogue(accC, lC, qbaseC);
}

// ---------------------------------------------------------------------------
extern "C" void kernel_launch(void* const* d_in, const int* in_sizes, int n_in,
                              void* d_out, int out_size, void* d_ws, size_t ws_size,
                              hipStream_t stream) {
  const float* x  = (const float*)d_in[0];
  const float* Wq = (const float*)d_in[1];
  const float* Wk = (const float*)d_in[2];
  const float* Wv = (const float*)d_in[3];
  const float* Wo = (const float*)d_in[4];
  const int* use_mask = (const int*)d_in[5];
  float* out = (float*)d_out;

  const size_t TSZ = (size_t)BS_ * DM_;   // 16,777,216 elems (32 MiB bf16)
  const size_t WSZ = (size_t)DM_ * DM_;   //  4,194,304 elems ( 8 MiB bf16)
  bf16_t* Qb  = (bf16_t*)d_ws;            // R0
  bf16_t* Kb  = Qb + TSZ;                 // R1
  bf16_t* Vt  = Kb + TSZ;                 // R2: Vt, then Wo_bf16 after attention
  bf16_t* xb  = Vt + TSZ;                 // R3: x_bf16, then Ob after projections
  bf16_t* Ob  = xb;
  bf16_t* Wob = Vt;
  // weight bf16 staging inside d_out (64 MiB fp32; fully overwritten at the end)
  bf16_t* wq = (bf16_t*)d_out;
  bf16_t* wk = wq + WSZ;
  bf16_t* wv = wk + WSZ;

  cvt_bf16<<<(int)(TSZ / 8 / 256), 256, 0, stream>>>(x,  xb, (int)(TSZ / 8));
  cvt_bf16<<<(int)(WSZ / 8 / 256), 256, 0, stream>>>(Wq, wq, (int)(WSZ / 8));
  cvt_bf16<<<(int)(WSZ / 8 / 256), 256, 0, stream>>>(Wk, wk, (int)(WSZ / 8));
  cvt_bf16<<<(int)(WSZ / 8 / 256), 256, 0, stream>>>(Wv, wv, (int)(WSZ / 8));

  dim3 gG(256);                      // (M/256)*(N/256) = 32*8
  gemm256<bf16_t, false><<<gG, 512, 0, stream>>>(xb, wq, Qb, BS_, DM_, DM_);
  gemm256<bf16_t, false><<<gG, 512, 0, stream>>>(xb, wk, Kb, BS_, DM_, DM_);
  gemm256<bf16_t, true ><<<gG, 512, 0, stream>>>(xb, wv, Vt, BS_, DM_, DM_);

  dim3 gA(16, 64);                   // 1024 balanced dual-q blocks
  attn_kernel<<<gA, 256, 0, stream>>>(Qb, Kb, Vt, Ob, use_mask);

  cvt_bf16<<<(int)(WSZ / 8 / 256), 256, 0, stream>>>(Wo, Wob, (int)(WSZ / 8));
  gemm256<float, false><<<gG, 512, 0, stream>>>(Ob, Wob, out, BS_, DM_, DM_);
}

// Round 7
// 623.099 us; speedup vs baseline: 1.1087x; 1.1087x over previous
//
#include <hip/hip_runtime.h>
#include <hip/hip_bf16.h>

typedef __bf16 bf16_t;
typedef __bf16 bf16x8 __attribute__((ext_vector_type(8)));
typedef float f32x4 __attribute__((ext_vector_type(4)));

#define B_  4
#define S_  2048
#define H_  16
#define DK_ 128
#define DM_ 2048
#define BS_ (B_ * S_)          // 8192 rows

static __device__ __forceinline__ f32x4 mfma16(bf16x8 a, bf16x8 b, f32x4 c) {
  return __builtin_amdgcn_mfma_f32_16x16x32_bf16(a, b, c, 0, 0, 0);
}

// async global->LDS 16B copy. lds base must be wave-uniform; HW scatters lane*16.
static __device__ __forceinline__ void async_copy16(const bf16_t* g, bf16_t* l) {
  __builtin_amdgcn_global_load_lds(
      (const __attribute__((address_space(1))) void*)g,
      (__attribute__((address_space(3))) void*)l, 16, 0, 0);
}

// raw workgroup barrier WITHOUT the vmcnt(0)/lgkmcnt(0) drain __syncthreads
// emits; "memory" clobber = compiler fence so ds_read/global_load_lds can't
// be reordered across the buffer-handoff point.
#define BARRIER() asm volatile("s_barrier" ::: "memory")

// DPP row_ror (within 16-lane row) on f32 -- cross-lane reduce on the VALU pipe.
template <int CTRL>
static __device__ __forceinline__ float dpp_rorf(float x) {
  return __builtin_bit_cast(float,
      __builtin_amdgcn_update_dpp(0, __builtin_bit_cast(int, x), CTRL, 0xF, 0xF, true));
}
static __device__ __forceinline__ float rowmax16(float r) {
  r = fmaxf(r, dpp_rorf<0x121>(r));
  r = fmaxf(r, dpp_rorf<0x122>(r));
  r = fmaxf(r, dpp_rorf<0x124>(r));
  r = fmaxf(r, dpp_rorf<0x128>(r));
  return r;
}
static __device__ __forceinline__ float rowsum16(float r) {
  r += dpp_rorf<0x121>(r);
  r += dpp_rorf<0x122>(r);
  r += dpp_rorf<0x124>(r);
  r += dpp_rorf<0x128>(r);
  return r;
}

struct ChainOn  { static constexpr bool v = true;  };
struct ChainOff { static constexpr bool v = false; };

// ---------------------------------------------------------------------------
// fp32 -> bf16 elementwise convert (8 elems/thread)
// ---------------------------------------------------------------------------
__global__ __launch_bounds__(256) void cvt_bf16(const float* __restrict__ in,
                                                bf16_t* __restrict__ out, int n8) {
  int i = blockIdx.x * 256 + threadIdx.x;
  if (i < n8) {
    const float4* p = (const float4*)in + (size_t)i * 2;
    float4 f0 = p[0], f1 = p[1];
    bf16x8 r;
    r[0] = (bf16_t)f0.x; r[1] = (bf16_t)f0.y; r[2] = (bf16_t)f0.z; r[3] = (bf16_t)f0.w;
    r[4] = (bf16_t)f1.x; r[5] = (bf16_t)f1.y; r[6] = (bf16_t)f1.z; r[7] = (bf16_t)f1.w;
    ((bf16x8*)out)[i] = r;
  }
}

// ---------------------------------------------------------------------------
// C[M,N] = A[M,K] * B[N,K]^T -- 256x256 tile, BK=64, 8 waves (2M x 4N),
// 4-phase-per-K-tile deep pipeline (T3+T4). r6 post-mortem: __syncthreads
// drained vmcnt to 0 every phase (compiler emits s_waitcnt vmcnt(0) before
// s_barrier), defeating the counted pipeline -> r6 ran at the old ~570 TF.
// This version uses raw s_barrier (BARRIER) so the counted vmcnt(8) at
// phases 1/3 is the ONLY vmem wait in the loop (never 0 in-loop).
//
// Ledger (per wave, 2 loads/phase; issues p0:A-kh1(t+1) p1:B-kh1(t+1)
// p2:A-kh0(t+2) p3:B-kh0(t+2); steady-state outstanding 12 at each wait):
//   W1 (end p1, vmcnt(8)): drains kh1(t)   -> read at phases 2,3 of t.
//   W2 (end p3, vmcnt(8)): drains kh0(t+1) -> read at phase 0 of t+1.
// Overwrite safety: a phase's ds_reads retire (compiler lgkmcnt before MFMA
// use) before that phase's end BARRIER; the overwriting stage is issued only
// after that barrier. Epilogue tiles always-issue with K-source clamped into
// dead slots (uniform ledger); final vmcnt(0) drain before s_endpgm so no
// lds-DMA lands after LDS is reallocated.
//
// Swizzle (T2): LDS row = 32 cols = 4 chunks of 8; logical chunk q stored at
// p = q ^ s(r), s(r) = (r + (r>>2)) & 3. global_load_lds dest stays linear;
// SOURCE chunk is inverse-swizzled; ds_read applies the XOR. (refcheck'd r6)
// VTOUT: write C per-head-transposed into Vt layout [(b*16+h)*128+d][s].
// ---------------------------------------------------------------------------
template <typename TC, bool VTOUT>
__global__ __launch_bounds__(512, 2) void gemm256(const bf16_t* __restrict__ A,
                                                  const bf16_t* __restrict__ B,
                                                  TC* __restrict__ C,
                                                  int M, int N, int K) {
  __shared__ bf16_t Ab[2][2][256 * 32];   // [dbuf][khalf][row*32+col] 64 KiB
  __shared__ bf16_t Bb[2][2][256 * 32];   // 64 KiB

  const int tid  = threadIdx.x;
  const int wave = tid >> 6;              // 0..7
  const int lane = tid & 63;
  const int quad = lane >> 4;
  const int l16  = lane & 15;
  const int wm   = (wave >> 2) * 128;     // wave's A half (M)
  const int wn   = (wave & 3) * 64;       // wave's B quarter (N)

  // XCD-bijective remap: 256 blocks; xcd owns a contiguous 4x8 tile stripe.
  const int bid = (int)blockIdx.x;
  const int xcd = bid & 7;
  const int idx = bid >> 3;               // 0..31
  const int bm  = (xcd * 4 + (idx >> 3)) * 256;
  const int bn  = (idx & 7) * 256;

  // --- staging geometry (per kh-stage: 2 instructions/wave, 16 rows each) ---
  const int p_ = lane & 3;                // chunk-in-row the HW writes
  const int r0 = wave * 32 + (lane >> 2); // instruction 0 row
  const int r1 = r0 + 16;                 // instruction 1 row
  const int s0 = (r0 + (r0 >> 2)) & 3;
  const int s1 = (r1 + (r1 >> 2)) & 3;
  const size_t aO0 = (size_t)(bm + r0) * K + (p_ ^ s0) * 8;
  const size_t aO1 = (size_t)(bm + r1) * K + (p_ ^ s1) * 8;
  const size_t bO0 = (size_t)(bn + r0) * K + (p_ ^ s0) * 8;
  const size_t bO1 = (size_t)(bn + r1) * K + (p_ ^ s1) * 8;
  const int ldsW = wave * 1024;           // wave-uniform elem base (+512 for i1)

  auto stA = [&](int slot, int kh, int kt) __attribute__((always_inline)) {
    const int c = kt * 64 + kh * 32;
    bf16_t* d = &Ab[slot][kh][ldsW];
    async_copy16(A + aO0 + c, d);
    async_copy16(A + aO1 + c, d + 512);
  };
  auto stB = [&](int slot, int kh, int kt) __attribute__((always_inline)) {
    const int c = kt * 64 + kh * 32;
    bf16_t* d = &Bb[slot][kh][ldsW];
    async_copy16(B + bO0 + c, d);
    async_copy16(B + bO1 + c, d + 512);
  };

  // --- fragment-read bases (s(row) is lane-only for 16-aligned row bases) ---
  const int sw  = (l16 + (l16 >> 2)) & 3;
  const int qs  = (quad ^ sw) * 8;
  const int arB = (wm + l16) * 32 + qs;   // + i*512 (+2048 for m-half 1)
  const int brB = (wn + l16) * 32 + qs;   // + n*512

  f32x4 acc[8][4];
#pragma unroll
  for (int i = 0; i < 8; ++i)
#pragma unroll
    for (int j = 0; j < 4; ++j) acc[i][j] = (f32x4){0.f, 0.f, 0.f, 0.f};

  const int NT = K >> 6;                  // K-tiles (BK=64)

  // prologue: kh0(0), kh1(0) -> buf0; kh0(1) -> buf1. 12 loads/wave.
  stA(0, 0, 0); stB(0, 0, 0);
  stA(0, 1, 0); stB(0, 1, 0);
  { int k1 = NT > 1 ? 1 : 0; stA(1, 0, k1); stB(1, 0, k1); }
  asm volatile("s_waitcnt vmcnt(8)" ::: "memory");   // kh0(0) resident
  BARRIER();

  for (int t = 0; t < NT; ++t) {
    const int cur = t & 1, nxt = cur ^ 1;
    const int tp1 = (t + 1 < NT) ? t + 1 : NT - 1;   // clamped sources
    const int tp2 = (t + 2 < NT) ? t + 2 : NT - 1;
    bf16x8 af[4], bfr[4];

    // ---- phase 0: ks=0, m-half 0 | stage A-kh1(t+1) ----
#pragma unroll
    for (int i = 0; i < 4; ++i)
      af[i] = *(const bf16x8*)(&Ab[cur][0][arB + i * 512]);
#pragma unroll
    for (int n = 0; n < 4; ++n)
      bfr[n] = *(const bf16x8*)(&Bb[cur][0][brB + n * 512]);
    stA(nxt, 1, tp1);
    BARRIER();
    __builtin_amdgcn_s_setprio(1);
#pragma unroll
    for (int i = 0; i < 4; ++i)
#pragma unroll
      for (int n = 0; n < 4; ++n) acc[i][n] = mfma16(af[i], bfr[n], acc[i][n]);
    __builtin_amdgcn_s_setprio(0);
    BARRIER();

    // ---- phase 1: ks=0, m-half 1 | stage B-kh1(t+1) | W1 ----
#pragma unroll
    for (int i = 0; i < 4; ++i)
      af[i] = *(const bf16x8*)(&Ab[cur][0][arB + 2048 + i * 512]);
    stB(nxt, 1, tp1);
    BARRIER();
    __builtin_amdgcn_s_setprio(1);
#pragma unroll
    for (int i = 0; i < 4; ++i)
#pragma unroll
      for (int n = 0; n < 4; ++n)
        acc[4 + i][n] = mfma16(af[i], bfr[n], acc[4 + i][n]);
    __builtin_amdgcn_s_setprio(0);
    asm volatile("s_waitcnt vmcnt(8)" ::: "memory");  // kh1(t) resident
    BARRIER();

    // ---- phase 2: ks=1, m-half 0 | stage A-kh0(t+2) ----
#pragma unroll
    for (int i = 0; i < 4; ++i)
      af[i] = *(const bf16x8*)(&Ab[cur][1][arB + i * 512]);
#pragma unroll
    for (int n = 0; n < 4; ++n)
      bfr[n] = *(const bf16x8*)(&Bb[cur][1][brB + n * 512]);
    stA(cur, 0, tp2);
    BARRIER();
    __builtin_amdgcn_s_setprio(1);
#pragma unroll
    for (int i = 0; i < 4; ++i)
#pragma unroll
      for (int n = 0; n < 4; ++n) acc[i][n] = mfma16(af[i], bfr[n], acc[i][n]);
    __builtin_amdgcn_s_setprio(0);
    BARRIER();

    // ---- phase 3: ks=1, m-half 1 | stage B-kh0(t+2) | W2 ----
#pragma unroll
    for (int i = 0; i < 4; ++i)
      af[i] = *(const bf16x8*)(&Ab[cur][1][arB + 2048 + i * 512]);
    stB(cur, 0, tp2);
    BARRIER();
    __builtin_amdgcn_s_setprio(1);
#pragma unroll
    for (int i = 0; i < 4; ++i)
#pragma unroll
      for (int n = 0; n < 4; ++n)
        acc[4 + i][n] = mfma16(af[i], bfr[n], acc[4 + i][n]);
    __builtin_amdgcn_s_setprio(0);
    asm volatile("s_waitcnt vmcnt(8)" ::: "memory");  // kh0(t+1) resident
    BARRIER();
  }

  // drain remaining lds-DMA before s_endpgm (LDS may be reallocated).
  asm volatile("s_waitcnt vmcnt(0)" ::: "memory");

  // epilogue: C/D layout row = quad*4+v, col = l16 per 16x16 fragment
#pragma unroll
  for (int mt = 0; mt < 8; ++mt)
#pragma unroll
    for (int nt = 0; nt < 4; ++nt)
#pragma unroll
      for (int v = 0; v < 4; ++v) {
        int row = bm + wm + mt * 16 + quad * 4 + v;
        int col = bn + wn + nt * 16 + l16;
        if constexpr (VTOUT) {
          // row = b*S+s, col = h*128+d -> Vt[((b*16+h)*128+d)*S + s]
          size_t o = (size_t)(((row >> 11) * 16 + (col >> 7)) * 128 + (col & 127)) * S_ +
                     (row & 2047);
          C[o] = (TC)acc[mt][nt][v];
        } else {
          C[(size_t)row * N + col] = (TC)acc[mt][nt][v];
        }
      }
}

// ---------------------------------------------------------------------------
// Flash attention, dual-chain load-balanced version (measured 153.9 us r5):
//  * One workgroup owns TWO q-blocks {qa=31-p, qc=p}: constant 33 work-units.
//  * Both chains consume the SAME staged K/V tile (shared kf/vf ds_reads).
//  * K/V double-buffered, global_load_lds issued one tile ahead.
//  * XOR-swizzled LDS, inverse-swizzled global sources.
//  * DPP row_ror softmax reductions; Q direct global->reg; defer-max; setprio.
// LDS: Ks 32K + Vs 32K + Ps 16K = 80KB -> 2 blocks/CU.
// Q,K: [b*S+s][h*128+d] bf16.  VT: [(b*16+h)*128+d][s] bf16.  O like Q.
// ---------------------------------------------------------------------------
__global__ __launch_bounds__(256, 2) void attn_kernel(const bf16_t* __restrict__ Q,
                                                      const bf16_t* __restrict__ K,
                                                      const bf16_t* __restrict__ VT,
                                                      bf16_t* __restrict__ O,
                                                      const int* __restrict__ use_mask) {
  __shared__ bf16_t Ks[2 * 64 * 128];   // [buf][k][d], XOR-swizzled
  __shared__ bf16_t Vs[2 * 128 * 64];   // [buf][d][k], XOR-swizzled
  __shared__ bf16_t Ps[2 * 4 * 16 * 64];// [chain][wave][16][64], XOR-swizzled

  const int tid  = threadIdx.x;
  const int wave = tid >> 6;
  const int lane = tid & 63;
  const int quad = lane >> 4;
  const int l16  = lane & 15;

  const int lid  = (int)(blockIdx.y * gridDim.x + blockIdx.x);
  const int xcd  = lid & 7;
  const int t8   = lid >> 3;                 // 0..127
  const int bh   = xcd + ((t8 >> 4) << 3);   // 8 heads per XCD
  const int pair = t8 & 15;
  const int qa   = 31 - pair;                // heavy q-block (17..32 tiles)
  const int qc   = pair;                     // light q-block (1..16 tiles)
  const int b = bh >> 4, h = bh & 15;
  const int maskflag = *use_mask;

  const size_t qbaseA = ((size_t)b * S_ + (size_t)qa * 64) * DM_ + h * DK_;
  const size_t qbaseC = ((size_t)b * S_ + (size_t)qc * 64) * DM_ + h * DK_;

  int skO[4], svO[4];
#pragma unroll
  for (int p = 0; p < 4; ++p) {
    int rK = p * 16 + wave * 4 + quad;
    skO[p] = rK * DM_ + ((l16 ^ (rK & 7)) * 8);
    int dV = p * 32 + wave * 8 + (lane >> 3);
    svO[p] = dV * S_ + (((lane & 7) ^ (dV & 7)) * 8);
  }

  const bf16_t* Kbase = K + (size_t)b * S_ * DM_ + h * DK_;
  const bf16_t* Vbase = VT + (size_t)bh * DK_ * S_;

  auto stage_kv = [&](int j, int buf) __attribute__((always_inline)) {
    const bf16_t* kb = Kbase + (size_t)j * 64 * DM_;
    const bf16_t* vb = Vbase + (size_t)j * 64;
    bf16_t* kl = Ks + buf * 8192 + wave * 512;
    bf16_t* vl = Vs + buf * 8192 + wave * 512;
#pragma unroll
    for (int p = 0; p < 4; ++p) {
      async_copy16(kb + skO[p], kl + p * 2048);
      async_copy16(vb + svO[p], vl + p * 2048);
    }
  };

  bf16x8 qfA[4], qfC[4];
#pragma unroll
  for (int kk = 0; kk < 4; ++kk) {
    size_t ro = (size_t)(wave * 16 + l16) * DM_ + kk * 32 + quad * 8;
    qfA[kk] = *(const bf16x8*)(Q + qbaseA + ro);
    qfC[kk] = *(const bf16x8*)(Q + qbaseC + ro);
  }

  stage_kv(0, 0);

  f32x4 accA[8], accC[8];
#pragma unroll
  for (int i = 0; i < 8; ++i) {
    accA[i] = (f32x4){0.f, 0.f, 0.f, 0.f};
    accC[i] = (f32x4){0.f, 0.f, 0.f, 0.f};
  }
  float mA[4], lA[4], mC[4], lC[4];
#pragma unroll
  for (int v = 0; v < 4; ++v) {
    mA[v] = -INFINITY; lA[v] = 0.f;
    mC[v] = -INFINITY; lC[v] = 0.f;
  }

  bf16_t* PwA = Ps + wave * 1024;
  bf16_t* PwC = Ps + 4096 + wave * 1024;

  const float c1 = 0.08838834764831845f * 1.4426950408889634f;

  const int ntA = maskflag ? qa + 1 : (S_ / 64);
  const int ntC = maskflag ? qc + 1 : (S_ / 64);

  auto softmax_chain = [&](f32x4 (&s)[4], float (&mrow)[4], float (&lrow)[4],
                           f32x4 (&acc)[8], bf16_t* Pw, bool masked)
      __attribute__((always_inline)) {
#pragma unroll
    for (int v = 0; v < 4; ++v) {
      float x[4];
#pragma unroll
      for (int nt = 0; nt < 4; ++nt) {
        float y = s[nt][v] * c1;
        if (masked) {
          int kg = nt * 16 + l16;
          int qg = wave * 16 + quad * 4 + v;
          if (kg > qg) y = -INFINITY;
        }
        x[nt] = y;
      }
      float r = fmaxf(fmaxf(x[0], x[1]), fmaxf(x[2], x[3]));
      r = rowmax16(r);
      float m = mrow[v];
      if (r > m + 8.f) {
        float alpha = __builtin_amdgcn_exp2f(m - r);
        lrow[v] *= alpha;
#pragma unroll
        for (int dt = 0; dt < 8; ++dt) acc[dt][v] *= alpha;
        mrow[v] = r;
        m = r;
      }
      float rs = 0.f;
      int prow = quad * 4 + v;
#pragma unroll
      for (int nt = 0; nt < 4; ++nt) {
        float p = __builtin_amdgcn_exp2f(x[nt] - m);
        rs += p;
        Pw[prow * 64 + ((nt * 16 + l16) ^ ((prow & 7) << 3))] = (bf16_t)p;
      }
      lrow[v] += rowsum16(rs);
    }
  };

  auto body = [&](auto DOC, int cur, bool maskedA, bool maskedC)
      __attribute__((always_inline)) {
    constexpr bool doC = decltype(DOC)::v;
    const bf16_t* KsB = Ks + cur * 8192;
    const bf16_t* VsB = Vs + cur * 8192;

    f32x4 sA[4], sC[4];
#pragma unroll
    for (int nt = 0; nt < 4; ++nt) {
      sA[nt] = (f32x4){0.f, 0.f, 0.f, 0.f};
      sC[nt] = (f32x4){0.f, 0.f, 0.f, 0.f};
    }
    __builtin_amdgcn_s_setprio(1);
#pragma unroll
    for (int kk = 0; kk < 4; ++kk) {
#pragma unroll
      for (int nt = 0; nt < 4; ++nt) {
        bf16x8 kf = *(const bf16x8*)(KsB + (nt * 16 + l16) * 128 +
                                     ((kk * 32 + quad * 8) ^ ((l16 & 7) << 3)));
        sA[nt] = mfma16(qfA[kk], kf, sA[nt]);
        if constexpr (doC) sC[nt] = mfma16(qfC[kk], kf, sC[nt]);
      }
    }
    __builtin_amdgcn_s_setprio(0);

    softmax_chain(sA, mA, lA, accA, PwA, maskedA);
    if constexpr (doC) softmax_chain(sC, mC, lC, accC, PwC, maskedC);

    __builtin_amdgcn_s_setprio(1);
#pragma unroll
    for (int kk = 0; kk < 2; ++kk) {
      bf16x8 pfA = *(const bf16x8*)(PwA + l16 * 64 +
                                    ((kk * 32 + quad * 8) ^ ((l16 & 7) << 3)));
      bf16x8 pfC = {};
      if constexpr (doC)
        pfC = *(const bf16x8*)(PwC + l16 * 64 +
                               ((kk * 32 + quad * 8) ^ ((l16 & 7) << 3)));
#pragma unroll
      for (int dt = 0; dt < 8; ++dt) {
        bf16x8 vf = *(const bf16x8*)(VsB + (dt * 16 + l16) * 64 +
                                     ((kk * 32 + quad * 8) ^ ((l16 & 7) << 3)));
        accA[dt] = mfma16(pfA, vf, accA[dt]);
        if constexpr (doC) accC[dt] = mfma16(pfC, vf, accC[dt]);
      }
    }
    __builtin_amdgcn_s_setprio(0);
  };

  __syncthreads();

  for (int t = 0; t < ntA; ++t) {
    const int cur = t & 1;
    if (t + 1 < ntA) stage_kv(t + 1, cur ^ 1);
    const bool mAf = maskflag && (t == qa);
    if (t < ntC)
      body(ChainOn{},  cur, mAf, maskflag && (t == qc));
    else
      body(ChainOff{}, cur, mAf, false);
    __syncthreads();
  }

  auto epilogue = [&](f32x4 (&acc)[8], float (&lrow)[4], size_t qbase)
      __attribute__((always_inline)) {
    float rl[4];
#pragma unroll
    for (int v = 0; v < 4; ++v) rl[v] = __builtin_amdgcn_rcpf(lrow[v]);
#pragma unroll
    for (int dt = 0; dt < 8; ++dt)
#pragma unroll
      for (int v = 0; v < 4; ++v) {
        int qr = wave * 16 + quad * 4 + v;
        O[qbase + (size_t)qr * DM_ + dt * 16 + l16] = (bf16_t)(acc[dt][v] * rl[v]);
      }
  };
  epilogue(accA, lA, qbaseA);
  epilogue(accC, lC, qbaseC);
}

// ---------------------------------------------------------------------------
extern "C" void kernel_launch(void* const* d_in, const int* in_sizes, int n_in,
                              void* d_out, int out_size, void* d_ws, size_t ws_size,
                              hipStream_t stream) {
  const float* x  = (const float*)d_in[0];
  const float* Wq = (const float*)d_in[1];
  const float* Wk = (const float*)d_in[2];
  const float* Wv = (const float*)d_in[3];
  const float* Wo = (const float*)d_in[4];
  const int* use_mask = (const int*)d_in[5];
  float* out = (float*)d_out;

  const size_t TSZ = (size_t)BS_ * DM_;   // 16,777,216 elems (32 MiB bf16)
  const size_t WSZ = (size_t)DM_ * DM_;   //  4,194,304 elems ( 8 MiB bf16)
  bf16_t* Qb  = (bf16_t*)d_ws;            // R0
  bf16_t* Kb  = Qb + TSZ;                 // R1
  bf16_t* Vt  = Kb + TSZ;                 // R2: Vt, then Wo_bf16 after attention
  bf16_t* xb  = Vt + TSZ;                 // R3: x_bf16, then Ob after projections
  bf16_t* Ob  = xb;
  bf16_t* Wob = Vt;
  // weight bf16 staging inside d_out (64 MiB fp32; fully overwritten at the end)
  bf16_t* wq = (bf16_t*)d_out;
  bf16_t* wk = wq + WSZ;
  bf16_t* wv = wk + WSZ;

  cvt_bf16<<<(int)(TSZ / 8 / 256), 256, 0, stream>>>(x,  xb, (int)(TSZ / 8));
  cvt_bf16<<<(int)(WSZ / 8 / 256), 256, 0, stream>>>(Wq, wq, (int)(WSZ / 8));
  cvt_bf16<<<(int)(WSZ / 8 / 256), 256, 0, stream>>>(Wk, wk, (int)(WSZ / 8));
  cvt_bf16<<<(int)(WSZ / 8 / 256), 256, 0, stream>>>(Wv, wv, (int)(WSZ / 8));

  dim3 gG(256);                      // (M/256)*(N/256) = 32*8
  gemm256<bf16_t, false><<<gG, 512, 0, stream>>>(xb, wq, Qb, BS_, DM_, DM_);
  gemm256<bf16_t, false><<<gG, 512, 0, stream>>>(xb, wk, Kb, BS_, DM_, DM_);
  gemm256<bf16_t, true ><<<gG, 512, 0, stream>>>(xb, wv, Vt, BS_, DM_, DM_);

  dim3 gA(16, 64);                   // 1024 balanced dual-q blocks
  attn_kernel<<<gA, 256, 0, stream>>>(Qb, Kb, Vt, Ob, use_mask);

  cvt_bf16<<<(int)(WSZ / 8 / 256), 256, 0, stream>>>(Wo, Wob, (int)(WSZ / 8));
  gemm256<float, false><<<gG, 512, 0, stream>>>(Ob, Wob, out, BS_, DM_, DM_);
}